// Round 2
// baseline (162.272 us; speedup 1.0000x reference)
//
#include <hip/hip_runtime.h>

// RenderMeshColor: B=16, P=100000, F=200000
// Outputs (concatenated flat, float32):
//   points3d_bxfx9   [16,200000,9]  offset 0
//   points2d_bxfx6   [16,200000,6]  offset 28,800,000
//   normalz_bxfx1    [16,200000,1]  offset 48,000,000
//   tfcolor_bxfx9    [16,200000,9]  offset 51,200,000
//   normal1_bxfx3    [16,200000,3]  offset 80,000,000

constexpr int Bn = 16;
constexpr int Pn = 100000;
constexpr int Fn = 200000;

constexpr size_t O0 = 0;
constexpr size_t O1 = (size_t)Bn * Fn * 9;            // 28,800,000
constexpr size_t O2 = O1 + (size_t)Bn * Fn * 6;       // 48,000,000
constexpr size_t O3 = O2 + (size_t)Bn * Fn * 1;       // 51,200,000
constexpr size_t O4 = O3 + (size_t)Bn * Fn * 9;       // 80,000,000

// BLAS-order 3-term dot: c = fma(a2,b2, fma(a1,b1, rn(a0*b0)))
// Matches OpenBLAS/XLA sgemm k-ascending FMA accumulation (acc starts at 0).
__device__ __forceinline__ float dot3_blas(float a0, float a1, float a2,
                                           float b0, float b1, float b2) {
    return fmaf(a2, b2, fmaf(a1, b1, __fmul_rn(a0, b0)));
}

__global__ __launch_bounds__(256)
void render_mesh_kernel(const float* __restrict__ points,    // [B,P,3]
                        const float* __restrict__ tfcolor,   // [B,P,3]
                        const int*   __restrict__ faces,     // [F,3] (int32 per harness)
                        const float* __restrict__ cam_rot,   // [B,3,3]
                        const float* __restrict__ cam_pos,   // [B,3]
                        const float* __restrict__ cam_proj,  // [3]
                        float* __restrict__ out)
{
    const int f = blockIdx.x * blockDim.x + threadIdx.x;
    const int b = blockIdx.y;
    if (f >= Fn) return;

    // Per-batch camera params — uniform across the block, L1-cached.
    const float r00 = cam_rot[b * 9 + 0], r01 = cam_rot[b * 9 + 1], r02 = cam_rot[b * 9 + 2];
    const float r10 = cam_rot[b * 9 + 3], r11 = cam_rot[b * 9 + 4], r12 = cam_rot[b * 9 + 5];
    const float r20 = cam_rot[b * 9 + 6], r21 = cam_rot[b * 9 + 7], r22 = cam_rot[b * 9 + 8];
    const float c0 = cam_pos[b * 3 + 0], c1 = cam_pos[b * 3 + 1], c2 = cam_pos[b * 3 + 2];
    const float pj0 = cam_proj[0], pj1 = cam_proj[1], pj2 = cam_proj[2];

    const int i0 = faces[f * 3 + 0];
    const int i1 = faces[f * 3 + 1];
    const int i2 = faces[f * 3 + 2];
    const int idxs[3] = {i0, i1, i2};

    const float* pb = points  + (size_t)b * Pn * 3;
    const float* cb = tfcolor + (size_t)b * Pn * 3;

    float px[3][3];   // transformed vertex positions
    float col[3][3];  // gathered colors
    float xy[3][2];   // projected 2D

#pragma unroll
    for (int v = 0; v < 3; ++v) {
        const int id = idxs[v];
        const float x = pb[id * 3 + 0];
        const float y = pb[id * 3 + 1];
        const float z = pb[id * 3 + 2];
        // pts = points - cam_pos  (plain IEEE sub, no contraction possible)
        const float dx = __fsub_rn(x, c0);
        const float dy = __fsub_rn(y, c1);
        const float dz = __fsub_rn(z, c2);
        // pts @ rot_t : t[j] = sum_k d[k] * cam_rot[j][k], BLAS k-ascending FMA order
        const float tx = dot3_blas(dx, dy, dz, r00, r01, r02);
        const float ty = dot3_blas(dx, dy, dz, r10, r11, r12);
        const float tz = dot3_blas(dx, dy, dz, r20, r21, r22);
        px[v][0] = tx; px[v][1] = ty; px[v][2] = tz;
        // xy3 = pts * proj;  xy = xy3[:2] / xy3[2]   (all rn, non-contractible)
        const float xv = __fmul_rn(tx, pj0);
        const float yv = __fmul_rn(ty, pj1);
        const float zv = __fmul_rn(tz, pj2);
        xy[v][0] = __fdiv_rn(xv, zv);
        xy[v][1] = __fdiv_rn(yv, zv);
        col[v][0] = cb[id * 3 + 0];
        col[v][1] = cb[id * 3 + 1];
        col[v][2] = cb[id * 3 + 2];
    }

    // normal = cross(p1-p0, p2-p0)
    const float e1x = px[1][0] - px[0][0], e1y = px[1][1] - px[0][1], e1z = px[1][2] - px[0][2];
    const float e2x = px[2][0] - px[0][0], e2y = px[2][1] - px[0][1], e2z = px[2][2] - px[0][2];
    const float nx = e1y * e2z - e1z * e2y;
    const float ny = e1z * e2x - e1x * e2z;
    const float nz = e1x * e2y - e1y * e2x;
    const float len = sqrtf(nx * nx + ny * ny + nz * nz);
    const float inv = 1.0f / (len + 1e-15f);

    const size_t bf = (size_t)b * Fn + f;

    // points3d_bxfx9
    {
        float* o = out + O0 + bf * 9;
#pragma unroll
        for (int v = 0; v < 3; ++v) {
            o[v * 3 + 0] = px[v][0];
            o[v * 3 + 1] = px[v][1];
            o[v * 3 + 2] = px[v][2];
        }
    }
    // points2d_bxfx6
    {
        float* o = out + O1 + bf * 6;
#pragma unroll
        for (int v = 0; v < 3; ++v) {
            o[v * 2 + 0] = xy[v][0];
            o[v * 2 + 1] = xy[v][1];
        }
    }
    // normalz_bxfx1
    out[O2 + bf] = nz;
    // tfcolor_bxfx9
    {
        float* o = out + O3 + bf * 9;
#pragma unroll
        for (int v = 0; v < 3; ++v) {
            o[v * 3 + 0] = col[v][0];
            o[v * 3 + 1] = col[v][1];
            o[v * 3 + 2] = col[v][2];
        }
    }
    // normal1_bxfx3
    {
        float* o = out + O4 + bf * 3;
        o[0] = nx * inv;
        o[1] = ny * inv;
        o[2] = nz * inv;
    }
}

extern "C" void kernel_launch(void* const* d_in, const int* in_sizes, int n_in,
                              void* d_out, int out_size, void* d_ws, size_t ws_size,
                              hipStream_t stream) {
    const float* points   = (const float*)d_in[0];
    const float* tfcolor  = (const float*)d_in[1];
    const int*   faces    = (const int*)d_in[2];
    const float* cam_rot  = (const float*)d_in[3];
    const float* cam_pos  = (const float*)d_in[4];
    const float* cam_proj = (const float*)d_in[5];
    float* out = (float*)d_out;

    dim3 block(256);
    dim3 grid((Fn + 255) / 256, Bn);
    render_mesh_kernel<<<grid, block, 0, stream>>>(points, tfcolor, faces,
                                                   cam_rot, cam_pos, cam_proj, out);
}

// Round 3
// 145.024 us; speedup vs baseline: 1.1189x; 1.1189x over previous
//
#include <hip/hip_runtime.h>

// RenderMeshColor: B=16, P=100000, F=200000
// Outputs (concatenated flat, float32):
//   points3d_bxfx9   [16,200000,9]  offset 0
//   points2d_bxfx6   [16,200000,6]
//   normalz_bxfx1    [16,200000,1]
//   tfcolor_bxfx9    [16,200000,9]
//   normal1_bxfx3    [16,200000,3]

constexpr int Bn = 16;
constexpr int Pn = 100000;
constexpr int Fn = 200000;

constexpr size_t O0 = 0;
constexpr size_t O1 = (size_t)Bn * Fn * 9;            // 28,800,000
constexpr size_t O2 = O1 + (size_t)Bn * Fn * 6;       // 48,000,000
constexpr size_t O3 = O2 + (size_t)Bn * Fn * 1;       // 51,200,000
constexpr size_t O4 = O3 + (size_t)Bn * Fn * 9;       // 80,000,000

// BLAS-order 3-term dot: c = fma(a2,b2, fma(a1,b1, rn(a0*b0)))
__device__ __forceinline__ float dot3_blas(float a0, float a1, float a2,
                                           float b0, float b1, float b2) {
    return fmaf(a2, b2, fmaf(a1, b1, __fmul_rn(a0, b0)));
}

// Coalesced LDS->global flush: lane-contiguous float4 stores.
__device__ __forceinline__ void flush4(float* __restrict__ dst,
                                       const float* __restrict__ src,
                                       int nfloats, int tid) {
    const float4* s4 = (const float4*)src;
    float4* d4 = (float4*)dst;
    const int n4 = nfloats >> 2;   // nfloats is always a multiple of 4 here
    for (int i = tid; i < n4; i += 256) d4[i] = s4[i];
}

__global__ __launch_bounds__(256)
void render_mesh_kernel(const float* __restrict__ points,    // [B,P,3]
                        const float* __restrict__ tfcolor,   // [B,P,3]
                        const int*   __restrict__ faces,     // [F,3]
                        const float* __restrict__ cam_rot,   // [B,3,3]
                        const float* __restrict__ cam_pos,   // [B,3]
                        const float* __restrict__ cam_proj,  // [3]
                        float* __restrict__ out)
{
    __shared__ __align__(16) float s3d[256 * 9];
    __shared__ __align__(16) float s2d[256 * 6];
    __shared__ __align__(16) float snz[256];
    __shared__ __align__(16) float scl[256 * 9];
    __shared__ __align__(16) float sn1[256 * 3];

    const int t = threadIdx.x;
    const int blockStart = blockIdx.x * 256;
    const int f = blockStart + t;
    const int b = blockIdx.y;
    const int nvalid = min(256, Fn - blockStart);   // 256 or 64 (tail)

    if (f < Fn) {
        // Per-batch camera params — uniform across block (scalar loads).
        const float r00 = cam_rot[b * 9 + 0], r01 = cam_rot[b * 9 + 1], r02 = cam_rot[b * 9 + 2];
        const float r10 = cam_rot[b * 9 + 3], r11 = cam_rot[b * 9 + 4], r12 = cam_rot[b * 9 + 5];
        const float r20 = cam_rot[b * 9 + 6], r21 = cam_rot[b * 9 + 7], r22 = cam_rot[b * 9 + 8];
        const float c0 = cam_pos[b * 3 + 0], c1 = cam_pos[b * 3 + 1], c2 = cam_pos[b * 3 + 2];
        const float pj0 = cam_proj[0], pj1 = cam_proj[1], pj2 = cam_proj[2];

        const int i0 = faces[f * 3 + 0];
        const int i1 = faces[f * 3 + 1];
        const int i2 = faces[f * 3 + 2];
        const int idxs[3] = {i0, i1, i2};

        const float* pb = points  + (size_t)b * Pn * 3;
        const float* cb = tfcolor + (size_t)b * Pn * 3;

        float px[3][3];

#pragma unroll
        for (int v = 0; v < 3; ++v) {
            const int id = idxs[v];
            const float x = pb[id * 3 + 0];
            const float y = pb[id * 3 + 1];
            const float z = pb[id * 3 + 2];
            const float dx = __fsub_rn(x, c0);
            const float dy = __fsub_rn(y, c1);
            const float dz = __fsub_rn(z, c2);
            const float tx = dot3_blas(dx, dy, dz, r00, r01, r02);
            const float ty = dot3_blas(dx, dy, dz, r10, r11, r12);
            const float tz = dot3_blas(dx, dy, dz, r20, r21, r22);
            px[v][0] = tx; px[v][1] = ty; px[v][2] = tz;
            s3d[t * 9 + v * 3 + 0] = tx;
            s3d[t * 9 + v * 3 + 1] = ty;
            s3d[t * 9 + v * 3 + 2] = tz;
            const float zv = __fmul_rn(tz, pj2);
            s2d[t * 6 + v * 2 + 0] = __fdiv_rn(__fmul_rn(tx, pj0), zv);
            s2d[t * 6 + v * 2 + 1] = __fdiv_rn(__fmul_rn(ty, pj1), zv);
            scl[t * 9 + v * 3 + 0] = cb[id * 3 + 0];
            scl[t * 9 + v * 3 + 1] = cb[id * 3 + 1];
            scl[t * 9 + v * 3 + 2] = cb[id * 3 + 2];
        }

        // normal = cross(p1-p0, p2-p0)
        const float e1x = px[1][0] - px[0][0], e1y = px[1][1] - px[0][1], e1z = px[1][2] - px[0][2];
        const float e2x = px[2][0] - px[0][0], e2y = px[2][1] - px[0][1], e2z = px[2][2] - px[0][2];
        const float nx = e1y * e2z - e1z * e2y;
        const float ny = e1z * e2x - e1x * e2z;
        const float nz = e1x * e2y - e1y * e2x;
        const float len = sqrtf(nx * nx + ny * ny + nz * nz);
        const float inv = 1.0f / (len + 1e-15f);

        snz[t] = nz;
        sn1[t * 3 + 0] = nx * inv;
        sn1[t * 3 + 1] = ny * inv;
        sn1[t * 3 + 2] = nz * inv;
    }

    __syncthreads();

    // Coalesced flush. Block bases are 16B-aligned (chunk sizes 9216/6144/1024/
    // 9216/3072 B); nvalid (256 or 64) keeps every count a multiple of 4.
    const size_t bf0 = (size_t)b * Fn + blockStart;
    flush4(out + O0 + bf0 * 9, s3d, nvalid * 9, t);
    flush4(out + O1 + bf0 * 6, s2d, nvalid * 6, t);
    flush4(out + O2 + bf0 * 1, snz, nvalid * 1, t);
    flush4(out + O3 + bf0 * 9, scl, nvalid * 9, t);
    flush4(out + O4 + bf0 * 3, sn1, nvalid * 3, t);
}

extern "C" void kernel_launch(void* const* d_in, const int* in_sizes, int n_in,
                              void* d_out, int out_size, void* d_ws, size_t ws_size,
                              hipStream_t stream) {
    const float* points   = (const float*)d_in[0];
    const float* tfcolor  = (const float*)d_in[1];
    const int*   faces    = (const int*)d_in[2];
    const float* cam_rot  = (const float*)d_in[3];
    const float* cam_pos  = (const float*)d_in[4];
    const float* cam_proj = (const float*)d_in[5];
    float* out = (float*)d_out;

    dim3 block(256);
    dim3 grid((Fn + 255) / 256, Bn);
    render_mesh_kernel<<<grid, block, 0, stream>>>(points, tfcolor, faces,
                                                   cam_rot, cam_pos, cam_proj, out);
}